// Round 2
// baseline (124.167 us; speedup 1.0000x reference)
//
#include <hip/hip_runtime.h>

typedef __attribute__((ext_vector_type(8))) __bf16 bf16x8;
typedef __attribute__((ext_vector_type(4))) float floatx4;

__device__ __forceinline__ unsigned short f2bf(float f) {
    unsigned int u = __builtin_bit_cast(unsigned int, f);
    unsigned int r = u + 0x7FFFu + ((u >> 16) & 1u);
    return (unsigned short)(r >> 16);
}

// Prep: fp32 weight [512][64] -> bf16 table + per-row squared norms; zero loss slot.
__global__ void vq_prep(const float* __restrict__ w, unsigned short* __restrict__ wbf,
                        float* __restrict__ wsq, float* __restrict__ loss_out) {
    const int t = threadIdx.x;
    const int row = blockIdx.x * 4 + (t >> 6);
    const int c = t & 63;
    float v = w[row * 64 + c];
    wbf[row * 64 + c] = f2bf(v);
    float s = v * v;
#pragma unroll
    for (int off = 32; off; off >>= 1) s += __shfl_xor(s, off, 64);
    if (c == 0) wsq[row] = s;
    if (blockIdx.x == 0 && t == 0) loss_out[0] = 0.f;
}

__global__ void __launch_bounds__(256) vq_main(
    const float* __restrict__ in,            // [32][64][4096] NCHW (HW flattened)
    const float* __restrict__ w,             // [512][64] fp32
    const unsigned short* __restrict__ wbf,  // [512][64] bf16
    const float* __restrict__ wsq,           // [512]
    float* __restrict__ out,                 // [32][64][4096]
    float* __restrict__ loss) {
    __shared__ unsigned short xs[8 * 64 * 8];  // [g=d>>3][m][e=d&7] bf16
    __shared__ float wsqs[512];
    __shared__ float red_s[4][64];
    __shared__ int   red_i[4][64];
    __shared__ int   idx_final[64];
    __shared__ float wave_sum[4];

    const int t = threadIdx.x;
    const int lane = t & 63;
    const int wv = t >> 6;                 // wave 0..3
    const int b = blockIdx.x >> 6;         // batch
    const int s0 = (blockIdx.x & 63) << 6; // spatial tile start (64 positions)

    const float* in_base = in + ((size_t)b * 64) * 4096 + s0;

    // stage wsq (512 floats)
    wsqs[t] = wsq[t];
    wsqs[t + 256] = wsq[t + 256];

    // stage X tile: thread -> (c = co + t>>4, 4 consecutive spatial j)
    const int jj = (t & 15) * 4;
    const int c0 = t >> 4;  // 0..15
#pragma unroll
    for (int co = 0; co < 64; co += 16) {
        const int c = co + c0;
        floatx4 v = *(const floatx4*)(in_base + (size_t)c * 4096 + jj);
        const int g = c >> 3, e = c & 7;
        unsigned short* p = &xs[((g * 64 + jj) * 8) + e];
        p[0]  = f2bf(v[0]);
        p[8]  = f2bf(v[1]);
        p[16] = f2bf(v[2]);
        p[24] = f2bf(v[3]);
    }
    __syncthreads();

    // B fragments (X^T), one 16x32 fragment pair per m-tile, reused over all codes.
    bf16x8 Bf[4][2];
    {
        const int half = lane >> 4;   // 0..3
        const int mcol = lane & 15;
#pragma unroll
        for (int mt = 0; mt < 4; ++mt) {
            const int m = mt * 16 + mcol;
#pragma unroll
            for (int h = 0; h < 2; ++h) {
                const int g = h * 4 + half;
                Bf[mt][h] = *(const bf16x8*)&xs[(g * 64 + m) * 8];
            }
        }
    }

    float best_s[4];
    int   best_i[4];
#pragma unroll
    for (int mt = 0; mt < 4; ++mt) { best_s[mt] = 1e30f; best_i[mt] = 0; }

    const int code_row = lane & 15;
    const int kgrp = lane >> 4;
    // wave wv handles codes [wv*128, wv*128+128) => 8 code-tiles of 16
    for (int ct = wv * 8; ct < wv * 8 + 8; ++ct) {
        const int code_base = ct * 16;
        const unsigned short* arow = wbf + (code_base + code_row) * 64 + kgrp * 8;
        bf16x8 A0 = *(const bf16x8*)(arow);        // d 0..31 slice
        bf16x8 A1 = *(const bf16x8*)(arow + 32);   // d 32..63 slice
        floatx4 wq = *(const floatx4*)&wsqs[code_base + kgrp * 4];
#pragma unroll
        for (int mt = 0; mt < 4; ++mt) {
            floatx4 acc = {0.f, 0.f, 0.f, 0.f};
            acc = __builtin_amdgcn_mfma_f32_16x16x32_bf16(A0, Bf[mt][0], acc, 0, 0, 0);
            acc = __builtin_amdgcn_mfma_f32_16x16x32_bf16(A1, Bf[mt][1], acc, 0, 0, 0);
#pragma unroll
            for (int r = 0; r < 4; ++r) {
                const float sc = wq[r] - 2.f * acc[r];
                const int code = code_base + kgrp * 4 + r;
                if (sc < best_s[mt]) { best_s[mt] = sc; best_i[mt] = code; }
            }
        }
    }

    // reduce argmin across the 4 lanes sharing each output column (xor 16, 32)
#pragma unroll
    for (int mt = 0; mt < 4; ++mt) {
        float s = best_s[mt];
        int   i = best_i[mt];
#pragma unroll
        for (int d = 16; d < 64; d <<= 1) {
            const float s2 = __shfl_xor(s, d, 64);
            const int   i2 = __shfl_xor(i, d, 64);
            if (s2 < s || (s2 == s && i2 < i)) { s = s2; i = i2; }
        }
        if (lane < 16) { red_s[wv][mt * 16 + lane] = s; red_i[wv][mt * 16 + lane] = i; }
    }
    __syncthreads();
    // combine across waves (each wave covered a different 128-code span)
    if (t < 64) {
        float s = red_s[0][t];
        int   i = red_i[0][t];
#pragma unroll
        for (int w2 = 1; w2 < 4; ++w2) {
            const float s2 = red_s[w2][t];
            const int   i2 = red_i[w2][t];
            if (s2 < s || (s2 == s && i2 < i)) { s = s2; i = i2; }
        }
        idx_final[t] = i;
    }
    __syncthreads();

    // epilogue: gather fp32 code rows, write out (coalesced float4), accumulate loss
    int idxr[4];
    idxr[0] = idx_final[jj + 0];
    idxr[1] = idx_final[jj + 1];
    idxr[2] = idx_final[jj + 2];
    idxr[3] = idx_final[jj + 3];

    float lsum = 0.f;
    float* out_base = out + ((size_t)b * 64) * 4096 + s0;
#pragma unroll
    for (int co = 0; co < 64; co += 16) {
        const int c = co + c0;
        floatx4 xv = *(const floatx4*)(in_base + (size_t)c * 4096 + jj);
        floatx4 qv;
#pragma unroll
        for (int r = 0; r < 4; ++r) {
            const float wr = w[idxr[r] * 64 + c];
            qv[r] = wr;
            const float d = wr - xv[r];
            lsum += d * d;
        }
        *(floatx4*)(out_base + (size_t)c * 4096 + jj) = qv;
    }

#pragma unroll
    for (int off = 32; off; off >>= 1) lsum += __shfl_xor(lsum, off, 64);
    if (lane == 0) wave_sum[wv] = lsum;
    __syncthreads();
    if (t == 0) {
        const float bs = wave_sum[0] + wave_sum[1] + wave_sum[2] + wave_sum[3];
        atomicAdd(loss, bs * (1.25f / 8388608.f));
    }
}

extern "C" void kernel_launch(void* const* d_in, const int* in_sizes, int n_in,
                              void* d_out, int out_size, void* d_ws, size_t ws_size,
                              hipStream_t stream) {
    const float* in = (const float*)d_in[0];
    const float* w  = (const float*)d_in[1];
    float* out = (float*)d_out;
    float* loss = out + 8388608;  // second output (scalar), concatenated
    unsigned short* wbf = (unsigned short*)d_ws;                   // 64 KB bf16 codebook
    float* wsq = (float*)((char*)d_ws + 512 * 64 * 2);             // 2 KB norms

    vq_prep<<<128, 256, 0, stream>>>(w, wbf, wsq, loss);
    vq_main<<<2048, 256, 0, stream>>>(in, w, wbf, wsq, out, loss);
}

// Round 3
// 116.420 us; speedup vs baseline: 1.0665x; 1.0665x over previous
//
#include <hip/hip_runtime.h>

typedef __attribute__((ext_vector_type(8))) __bf16 bf16x8;
typedef __attribute__((ext_vector_type(4))) float floatx4;

__device__ __forceinline__ unsigned short f2bf(float f) {
    unsigned int u = __builtin_bit_cast(unsigned int, f);
    unsigned int r = u + 0x7FFFu + ((u >> 16) & 1u);
    return (unsigned short)(r >> 16);
}

// Prep: fp32 weight [512][64] -> bf16 table + per-row squared norms.
__global__ void vq_prep(const float* __restrict__ w, unsigned short* __restrict__ wbf,
                        float* __restrict__ wsq) {
    const int t = threadIdx.x;
    const int row = blockIdx.x * 4 + (t >> 6);
    const int c = t & 63;
    float v = w[row * 64 + c];
    wbf[row * 64 + c] = f2bf(v);
    float s = v * v;
#pragma unroll
    for (int off = 32; off; off >>= 1) s += __shfl_xor(s, off, 64);
    if (c == 0) wsq[row] = s;
}

__global__ void __launch_bounds__(256) vq_main(
    const float* __restrict__ in,            // [32][64][4096] NCHW (HW flattened)
    const float* __restrict__ w,             // [512][64] fp32
    const unsigned short* __restrict__ wbf,  // [512][64] bf16
    const float* __restrict__ wsq,           // [512]
    float* __restrict__ out,                 // [32][64][4096]
    float* __restrict__ partials) {          // [2048] per-block loss sums
    __shared__ unsigned short xs[8 * 64 * 8];  // [g=d>>3][m][e=d&7] bf16
    __shared__ float wsqs[512];
    __shared__ float red_s[4][64];
    __shared__ int   red_i[4][64];
    __shared__ int   idx_final[64];
    __shared__ float wave_sum[4];

    const int t = threadIdx.x;
    const int lane = t & 63;
    const int wv = t >> 6;                 // wave 0..3
    const int b = blockIdx.x >> 6;         // batch
    const int s0 = (blockIdx.x & 63) << 6; // spatial tile start (64 positions)

    const float* in_base = in + ((size_t)b * 64) * 4096 + s0;

    // stage wsq (512 floats)
    wsqs[t] = wsq[t];
    wsqs[t + 256] = wsq[t + 256];

    // stage X tile: thread -> (c = co + t>>4, 4 consecutive spatial j)
    const int jj = (t & 15) * 4;
    const int c0 = t >> 4;  // 0..15
#pragma unroll
    for (int co = 0; co < 64; co += 16) {
        const int c = co + c0;
        floatx4 v = *(const floatx4*)(in_base + (size_t)c * 4096 + jj);
        const int g = c >> 3, e = c & 7;
        unsigned short* p = &xs[((g * 64 + jj) * 8) + e];
        p[0]  = f2bf(v[0]);
        p[8]  = f2bf(v[1]);
        p[16] = f2bf(v[2]);
        p[24] = f2bf(v[3]);
    }
    __syncthreads();

    // B fragments (X^T), one 16x32 fragment pair per m-tile, reused over all codes.
    bf16x8 Bf[4][2];
    {
        const int half = lane >> 4;   // 0..3
        const int mcol = lane & 15;
#pragma unroll
        for (int mt = 0; mt < 4; ++mt) {
            const int m = mt * 16 + mcol;
#pragma unroll
            for (int h = 0; h < 2; ++h) {
                const int g = h * 4 + half;
                Bf[mt][h] = *(const bf16x8*)&xs[(g * 64 + m) * 8];
            }
        }
    }

    float best_s[4];
    int   best_i[4];
#pragma unroll
    for (int mt = 0; mt < 4; ++mt) { best_s[mt] = 1e30f; best_i[mt] = 0; }

    const int code_row = lane & 15;
    const int kgrp = lane >> 4;
    // wave wv handles codes [wv*128, wv*128+128) => 8 code-tiles of 16
#pragma unroll
    for (int cti = 0; cti < 8; ++cti) {
        const int ct = wv * 8 + cti;
        const int code_base = ct * 16;
        const unsigned short* arow = wbf + (code_base + code_row) * 64 + kgrp * 8;
        bf16x8 A0 = *(const bf16x8*)(arow);        // d 0..31 slice
        bf16x8 A1 = *(const bf16x8*)(arow + 32);   // d 32..63 slice
        floatx4 wq = *(const floatx4*)&wsqs[code_base + kgrp * 4];
#pragma unroll
        for (int mt = 0; mt < 4; ++mt) {
            floatx4 acc = {0.f, 0.f, 0.f, 0.f};
            acc = __builtin_amdgcn_mfma_f32_16x16x32_bf16(A0, Bf[mt][0], acc, 0, 0, 0);
            acc = __builtin_amdgcn_mfma_f32_16x16x32_bf16(A1, Bf[mt][1], acc, 0, 0, 0);
#pragma unroll
            for (int r = 0; r < 4; ++r) {
                const float sc = wq[r] - 2.f * acc[r];
                const int code = code_base + kgrp * 4 + r;
                if (sc < best_s[mt]) { best_s[mt] = sc; best_i[mt] = code; }
            }
        }
    }

    // reduce argmin across the 4 lanes sharing each output column (xor 16, 32)
#pragma unroll
    for (int mt = 0; mt < 4; ++mt) {
        float s = best_s[mt];
        int   i = best_i[mt];
#pragma unroll
        for (int d = 16; d < 64; d <<= 1) {
            const float s2 = __shfl_xor(s, d, 64);
            const int   i2 = __shfl_xor(i, d, 64);
            if (s2 < s || (s2 == s && i2 < i)) { s = s2; i = i2; }
        }
        if (lane < 16) { red_s[wv][mt * 16 + lane] = s; red_i[wv][mt * 16 + lane] = i; }
    }
    __syncthreads();
    // combine across waves (each wave covered a different 128-code span)
    if (t < 64) {
        float s = red_s[0][t];
        int   i = red_i[0][t];
#pragma unroll
        for (int w2 = 1; w2 < 4; ++w2) {
            const float s2 = red_s[w2][t];
            const int   i2 = red_i[w2][t];
            if (s2 < s || (s2 == s && i2 < i)) { s = s2; i = i2; }
        }
        idx_final[t] = i;
    }
    __syncthreads();

    // epilogue: gather fp32 code rows, write out (coalesced float4), accumulate loss
    int idxr[4];
    idxr[0] = idx_final[jj + 0];
    idxr[1] = idx_final[jj + 1];
    idxr[2] = idx_final[jj + 2];
    idxr[3] = idx_final[jj + 3];

    float lsum = 0.f;
    float* out_base = out + ((size_t)b * 64) * 4096 + s0;
#pragma unroll
    for (int co = 0; co < 64; co += 16) {
        const int c = co + c0;
        floatx4 xv = *(const floatx4*)(in_base + (size_t)c * 4096 + jj);
        floatx4 qv;
#pragma unroll
        for (int r = 0; r < 4; ++r) {
            const float wr = w[idxr[r] * 64 + c];
            qv[r] = wr;
            const float d = wr - xv[r];
            lsum += d * d;
        }
        *(floatx4*)(out_base + (size_t)c * 4096 + jj) = qv;
    }

#pragma unroll
    for (int off = 32; off; off >>= 1) lsum += __shfl_xor(lsum, off, 64);
    if (lane == 0) wave_sum[wv] = lsum;
    __syncthreads();
    if (t == 0) {
        partials[blockIdx.x] = wave_sum[0] + wave_sum[1] + wave_sum[2] + wave_sum[3];
    }
}

// Final: sum 2048 per-block partials -> scalar loss (no atomics anywhere).
__global__ void vq_reduce(const float* __restrict__ partials, float* __restrict__ loss) {
    const int t = threadIdx.x;
    float s = 0.f;
#pragma unroll
    for (int i = 0; i < 8; ++i) s += partials[t + i * 256];
#pragma unroll
    for (int off = 32; off; off >>= 1) s += __shfl_xor(s, off, 64);
    __shared__ float ws4[4];
    if ((t & 63) == 0) ws4[t >> 6] = s;
    __syncthreads();
    if (t == 0) loss[0] = (ws4[0] + ws4[1] + ws4[2] + ws4[3]) * (1.25f / 8388608.f);
}

extern "C" void kernel_launch(void* const* d_in, const int* in_sizes, int n_in,
                              void* d_out, int out_size, void* d_ws, size_t ws_size,
                              hipStream_t stream) {
    const float* in = (const float*)d_in[0];
    const float* w  = (const float*)d_in[1];
    float* out = (float*)d_out;
    float* loss = out + 8388608;  // second output (scalar), concatenated
    unsigned short* wbf = (unsigned short*)d_ws;                   // 64 KB bf16 codebook
    float* wsq = (float*)((char*)d_ws + 512 * 64 * 2);             // 2 KB norms
    float* partials = (float*)((char*)d_ws + 512 * 64 * 2 + 2048); // 8 KB per-block sums

    vq_prep<<<128, 256, 0, stream>>>(w, wbf, wsq);
    vq_main<<<2048, 256, 0, stream>>>(in, w, wbf, wsq, out, partials);
    vq_reduce<<<1, 256, 0, stream>>>(partials, loss);
}